// Round 9
// baseline (54.970 us; speedup 1.0000x reference)
//
#include <hip/hip_runtime.h>
#include <stdint.h>

// graph_smooth: x = node_features @ Emb; A[src,dst] = w (last write wins);
// out = A^3 @ x.  N=4096, E=131072, D_EMB=128, D_OUT=64, K=3.
//
// Launch-bound. Measured facts: in-kernel grid barriers 35-120us/sync
// (R3/R6) -> multi-dispatch; 5 graph nodes is the sync floor; LDS-staged
// bins required in hops (R7: -6us); embed-before-scatter in N1 (R8: scatter
// -first cost ~2us). This round: halve total workgroups (4608 -> 2304) to
// attack dispatch-issue rate -- hops 512 blocks x 2 rows/wave, scatter 256
// blocks x 2 edges/thread.
//   N0 memset(cnt,16KB) | N1 embed+scatter | N2 dedup+hop1 | N3 hop2 | N4 hop3
// Bins: pairs{dst,w_bits} 8B (hops) + eids 4B (dedup only). Dedup = numpy
// last-write-wins = max eid per (src,dst), run in hop1's wave; losers get
// w=0 written back so hops 2-3 see deduped bins.

#define N_NODES 4096
#define D_EMB   128
#define D_OUT   64

#define CAPN      128   // slots per row incl. duplicates; Poisson(32) tail ~1e-40
#define CAP_SHIFT 7

#define HOPBLK  512     // hop kernels: 2048 waves, 2 rows/wave
#define HOPWAVE 2048

// ---- N1: blocks 0..511 embed (2 rows/wave), 512..767 scatter (2 edges/thr) ----
__global__ void embed_scatter_kernel(const float* __restrict__ nf,
                                     const float* __restrict__ emb,
                                     float* __restrict__ x,
                                     const int* __restrict__ ei,
                                     const float* __restrict__ ew, int E,
                                     int* __restrict__ cnt,
                                     int2* __restrict__ pairs,
                                     int* __restrict__ eids) {
    if (blockIdx.x < 512) {
        // ---- embed: x[row,:] = nf[row,:] @ emb, rows gw and gw+2048 ----
        __shared__ float srow[4][D_EMB];
        int wave = threadIdx.x >> 6;
        int lane = threadIdx.x & 63;
        int gw   = blockIdx.x * 4 + wave;            // 0..2047
        for (int row = gw; row < N_NODES; row += 2048) {
            float2 a = ((const float2*)(nf + (size_t)row * D_EMB))[lane];
            srow[wave][2 * lane]     = a.x;
            srow[wave][2 * lane + 1] = a.y;
            __syncthreads();                          // uniform trip count
            float acc = 0.0f;
#pragma unroll 8
            for (int k = 0; k < D_EMB; ++k)
                acc = fmaf(srow[wave][k], emb[k * D_OUT + lane], acc);
            x[row * D_OUT + lane] = acc;
            __syncthreads();
        }
    } else {
        // ---- scatter: bin every edge (incl. duplicates) by src ----
        int t = (blockIdx.x - 512) * blockDim.x + threadIdx.x;  // 0..65535
        for (int e = t; e < E; e += 65536) {
            int src = ei[e];
            int dst = ei[E + e];
            int idx = atomicAdd(&cnt[src], 1);
            if (idx < CAPN) {
                int p = (src << CAP_SHIFT) + idx;
                int2 pr;
                pr.x = dst;
                pr.y = __float_as_int(ew[e]);
                pairs[p] = pr;
                eids[p]  = e;
            }
        }
    }
}

// ---- N2: per-row dedup (keep max eid per dst) + hop1; 2 rows/wave ----
__global__ void dedup_spmm_kernel(const int* __restrict__ cnt,
                                  int2* __restrict__ pairs,
                                  const int* __restrict__ eids,
                                  const float* __restrict__ x,
                                  float* __restrict__ y) {
    __shared__ int   sdst[4][CAPN];
    __shared__ int   seid[4][CAPN];
    __shared__ float sw[4][CAPN];

    int wave = threadIdx.x >> 6;
    int lane = threadIdx.x & 63;
    int gw   = blockIdx.x * 4 + wave;                // 0..2047

    for (int row = gw; row < N_NODES; row += HOPWAVE) {
        int c = cnt[row];
        if (c > CAPN) c = CAPN;
        int2* sp = pairs + ((long)row << CAP_SHIFT);
        const int* se = eids + ((long)row << CAP_SHIFT);

#pragma unroll
        for (int half = 0; half < 2; ++half) {
            int i = lane + half * 64;
            if (i < c) {
                int2 pr = sp[i];
                sdst[wave][i] = pr.x;
                sw[wave][i]   = __int_as_float(pr.y);
                seid[wave][i] = se[i];
            }
        }
        __syncthreads();

        // dedup: entry i loses if some j has same dst and larger eid
#pragma unroll
        for (int half = 0; half < 2; ++half) {
            int i = lane + half * 64;
            if (i < c) {
                int d = sdst[wave][i], id = seid[wave][i];
                bool loser = false;
                for (int j = 0; j < c; ++j)
                    loser |= (sdst[wave][j] == d) & (seid[wave][j] > id);
                if (loser) {
                    sw[wave][i] = 0.0f;
                    sp[i].y = 0;   // hops 2-3 see deduped weight
                }
            }
        }

        // hop 1, 8-deep gather ILP
        float acc = 0.0f;
        int i = 0;
        for (; i + 8 <= c; i += 8) {
            float vw[8], vx[8];
            int vd[8];
#pragma unroll
            for (int k = 0; k < 8; ++k) vw[k] = sw[wave][i + k];
#pragma unroll
            for (int k = 0; k < 8; ++k) vd[k] = sdst[wave][i + k];
#pragma unroll
            for (int k = 0; k < 8; ++k) vx[k] = x[vd[k] * D_OUT + lane];
#pragma unroll
            for (int k = 0; k < 8; ++k) acc = fmaf(vw[k], vx[k], acc);
        }
        for (; i < c; ++i)
            acc = fmaf(sw[wave][i], x[sdst[wave][i] * D_OUT + lane], acc);
        y[row * D_OUT + lane] = acc;
        __syncthreads();
    }
}

// ---- N3/N4: plain SpMM hop with LDS-staged 8B bins; 2 rows/wave ----
__global__ void spmm_kernel(const int* __restrict__ cnt,
                            const int2* __restrict__ pairs,
                            const float* __restrict__ x,
                            float* __restrict__ y) {
    __shared__ int   sdst[4][CAPN];
    __shared__ float sw[4][CAPN];

    int wave = threadIdx.x >> 6;
    int lane = threadIdx.x & 63;
    int gw   = blockIdx.x * 4 + wave;                // 0..2047

    for (int row = gw; row < N_NODES; row += HOPWAVE) {
        int c = cnt[row];
        if (c > CAPN) c = CAPN;
        const int2* sp = pairs + ((long)row << CAP_SHIFT);

#pragma unroll
        for (int half = 0; half < 2; ++half) {
            int i = lane + half * 64;
            if (i < c) {
                int2 pr = sp[i];
                sdst[wave][i] = pr.x;
                sw[wave][i]   = __int_as_float(pr.y);
            }
        }
        __syncthreads();

        float acc = 0.0f;
        int i = 0;
        for (; i + 8 <= c; i += 8) {
            float vw[8], vx[8];
            int vd[8];
#pragma unroll
            for (int k = 0; k < 8; ++k) vw[k] = sw[wave][i + k];
#pragma unroll
            for (int k = 0; k < 8; ++k) vd[k] = sdst[wave][i + k];
#pragma unroll
            for (int k = 0; k < 8; ++k) vx[k] = x[vd[k] * D_OUT + lane];
#pragma unroll
            for (int k = 0; k < 8; ++k) acc = fmaf(vw[k], vx[k], acc);
        }
        for (; i < c; ++i)
            acc = fmaf(sw[wave][i], x[sdst[wave][i] * D_OUT + lane], acc);
        y[row * D_OUT + lane] = acc;
        __syncthreads();
    }
}

extern "C" void kernel_launch(void* const* d_in, const int* in_sizes, int n_in,
                              void* d_out, int out_size, void* d_ws, size_t ws_size,
                              hipStream_t stream) {
    const float* nf  = (const float*)d_in[0];   // [N, 128]
    const float* emb = (const float*)d_in[1];   // [128, 64]
    const int*   ei  = (const int*)d_in[2];     // [2, E]
    const float* ew  = (const float*)d_in[3];   // [E]
    float* out = (float*)d_out;                 // [N, 64]

    const int E = in_sizes[3];

    // ---- workspace carve-out (256B-aligned) ----
    char* ws = (char*)d_ws;
    size_t o = 0;
    auto take = [&](size_t bytes) -> void* {
        void* p = ws + o;
        o += (bytes + 255) & ~(size_t)255;
        return p;
    };
    int*  cnt   = (int*)take((size_t)N_NODES * 4);
    int2* pairs = (int2*)take((size_t)N_NODES * CAPN * 8);
    int*  eids  = (int*)take((size_t)N_NODES * CAPN * 4);
    float* x0   = (float*)take((size_t)N_NODES * D_OUT * 4);
    float* x1   = (float*)take((size_t)N_NODES * D_OUT * 4);

    const int TB = 256;

    hipMemsetAsync(cnt, 0, (size_t)N_NODES * 4, stream);                 // N0
    embed_scatter_kernel<<<768, TB, 0, stream>>>(nf, emb, x0,            // N1
                                                 ei, ew, E, cnt, pairs, eids);
    dedup_spmm_kernel<<<HOPBLK, TB, 0, stream>>>(cnt, pairs, eids, x0, x1); // N2
    spmm_kernel<<<HOPBLK, TB, 0, stream>>>(cnt, pairs, x1, x0);             // N3
    spmm_kernel<<<HOPBLK, TB, 0, stream>>>(cnt, pairs, x0, out);            // N4
}

// Round 10
// 46.675 us; speedup vs baseline: 1.1777x; 1.1777x over previous
//
#include <hip/hip_runtime.h>
#include <stdint.h>

// graph_smooth: x = node_features @ Emb; A[src,dst] = w (last write wins);
// out = A^3 @ x.  N=4096, E=131072, D_EMB=128, D_OUT=64, K=3.
//
// Launch-bound. Measured: in-kernel grid barriers 35-120us/sync (R3/R6) ->
// multi-dispatch; 5 graph nodes = sync floor; LDS-staged bins required in
// hops (R7: +6us without); 1 row/wave, many small blocks (R9: 2 rows/wave
// +8.5us); embed-first in N1 (R8: scatter-first +~2us).
//
// This round: dedup fused INTO scatter via per-row open-addressed slots with
// 64-bit atomicMax. entry = (dst+1)<<49 | eid<<32 | w_bits; same (src,dst)
// lands in one slot, max eid wins = numpy last-write-wins. N2 becomes a
// plain hop (ballot-compact the 128 slots, then gather).
//   N0 memset(slots, 4MB) | N1 embed+scatter-dedup | N2 hop1 | N3 hop2 | N4 hop3

#define N_NODES 4096
#define D_EMB   128
#define D_OUT   64

#define RSLOTS     128   // open-addressed slots per row; load factor ~25%
#define RS_SHIFT   7

__device__ __forceinline__ uint32_t dhash(uint32_t d) {
    return (d * 2654435761u) >> 25;   // top 7 bits
}

// ---- N1: blocks 0..1023 embed (4 waves x 1 row), 1024..1535 scatter ----
__global__ void embed_scatter_kernel(const float* __restrict__ nf,
                                     const float* __restrict__ emb,
                                     float* __restrict__ x,
                                     const int* __restrict__ ei,
                                     const float* __restrict__ ew, int E,
                                     unsigned long long* __restrict__ slots) {
    if (blockIdx.x < 1024) {
        // ---- embed: x[row,:] = nf[row,:] @ emb ----
        __shared__ float srow[4][D_EMB];
        int wave = threadIdx.x >> 6;
        int lane = threadIdx.x & 63;
        int row  = blockIdx.x * 4 + wave;
        float2 a = ((const float2*)(nf + (size_t)row * D_EMB))[lane];
        srow[wave][2 * lane]     = a.x;
        srow[wave][2 * lane + 1] = a.y;
        __syncthreads();
        float acc = 0.0f;
#pragma unroll 8
        for (int k = 0; k < D_EMB; ++k)
            acc = fmaf(srow[wave][k], emb[k * D_OUT + lane], acc);
        x[row * D_OUT + lane] = acc;
    } else {
        // ---- scatter+dedup: open-addressed insert keyed by dst ----
        int e = (blockIdx.x - 1024) * blockDim.x + threadIdx.x;
        if (e >= E) return;
        int src = ei[e];
        int dst = ei[E + e];
        unsigned long long key = (unsigned long long)(dst + 1);
        unsigned long long entry = (key << 49)
                                 | ((unsigned long long)(uint32_t)e << 32)
                                 | (unsigned long long)__float_as_uint(ew[e]);
        unsigned long long* rs = slots + ((size_t)src << RS_SHIFT);
        uint32_t h = dhash((uint32_t)dst) & (RSLOTS - 1);
        while (true) {
            unsigned long long cur = rs[h];
            if ((cur >> 49) == key) { atomicMax(&rs[h], entry); break; }
            if (cur == 0ULL) {
                unsigned long long old = atomicCAS(&rs[h], 0ULL, entry);
                if (old == 0ULL) break;
                if ((old >> 49) == key) { atomicMax(&rs[h], entry); break; }
            }
            h = (h + 1) & (RSLOTS - 1);
        }
    }
}

// ---- N2/N3/N4: SpMM hop. Compact the row's 128 slots via ballot/popc into
// LDS, then 8-deep-ILP gather. One wave per row, 4 waves per block. ----
__global__ void spmm_kernel(const unsigned long long* __restrict__ slots,
                            const float* __restrict__ x,
                            float* __restrict__ y) {
    __shared__ int   sdst[4][RSLOTS];
    __shared__ float sw[4][RSLOTS];

    int wave = threadIdx.x >> 6;
    int lane = threadIdx.x & 63;
    int row  = blockIdx.x * 4 + wave;
    const unsigned long long* rs = slots + ((size_t)row << RS_SHIFT);

    unsigned long long e0 = rs[lane];
    unsigned long long e1 = rs[lane + 64];
    unsigned long long m0 = __ballot(e0 != 0ULL);
    unsigned long long m1 = __ballot(e1 != 0ULL);
    unsigned long long lt = (1ULL << lane) - 1ULL;
    int c0 = __popcll(m0);
    int c  = c0 + __popcll(m1);
    if (e0) {
        int p = __popcll(m0 & lt);
        sdst[wave][p] = (int)(e0 >> 49) - 1;
        sw[wave][p]   = __uint_as_float((uint32_t)e0);
    }
    if (e1) {
        int p = c0 + __popcll(m1 & lt);
        sdst[wave][p] = (int)(e1 >> 49) - 1;
        sw[wave][p]   = __uint_as_float((uint32_t)e1);
    }
    __syncthreads();

    float acc = 0.0f;
    int i = 0;
    for (; i + 8 <= c; i += 8) {
        float vw[8], vx[8];
        int vd[8];
#pragma unroll
        for (int k = 0; k < 8; ++k) vw[k] = sw[wave][i + k];
#pragma unroll
        for (int k = 0; k < 8; ++k) vd[k] = sdst[wave][i + k];
#pragma unroll
        for (int k = 0; k < 8; ++k) vx[k] = x[vd[k] * D_OUT + lane];
#pragma unroll
        for (int k = 0; k < 8; ++k) acc = fmaf(vw[k], vx[k], acc);
    }
    for (; i < c; ++i)
        acc = fmaf(sw[wave][i], x[sdst[wave][i] * D_OUT + lane], acc);
    y[row * D_OUT + lane] = acc;
}

extern "C" void kernel_launch(void* const* d_in, const int* in_sizes, int n_in,
                              void* d_out, int out_size, void* d_ws, size_t ws_size,
                              hipStream_t stream) {
    const float* nf  = (const float*)d_in[0];   // [N, 128]
    const float* emb = (const float*)d_in[1];   // [128, 64]
    const int*   ei  = (const int*)d_in[2];     // [2, E]
    const float* ew  = (const float*)d_in[3];   // [E]
    float* out = (float*)d_out;                 // [N, 64]

    const int E = in_sizes[3];

    // ---- workspace carve-out (256B-aligned) ----
    char* ws = (char*)d_ws;
    size_t o = 0;
    auto take = [&](size_t bytes) -> void* {
        void* p = ws + o;
        o += (bytes + 255) & ~(size_t)255;
        return p;
    };
    unsigned long long* slots =
        (unsigned long long*)take((size_t)N_NODES * RSLOTS * 8);   // 4 MB
    float* x0 = (float*)take((size_t)N_NODES * D_OUT * 4);
    float* x1 = (float*)take((size_t)N_NODES * D_OUT * 4);

    const int TB = 256;
    const int NB = N_NODES / 4;                       // 1024
    const int SB = (E + TB - 1) / TB;                 // 512

    hipMemsetAsync(slots, 0, (size_t)N_NODES * RSLOTS * 8, stream); // N0
    embed_scatter_kernel<<<NB + SB, TB, 0, stream>>>(nf, emb, x0,   // N1
                                                     ei, ew, E, slots);
    spmm_kernel<<<NB, TB, 0, stream>>>(slots, x0, x1);              // N2
    spmm_kernel<<<NB, TB, 0, stream>>>(slots, x1, x0);              // N3
    spmm_kernel<<<NB, TB, 0, stream>>>(slots, x0, out);             // N4
}

// Round 11
// 44.964 us; speedup vs baseline: 1.2225x; 1.0380x over previous
//
#include <hip/hip_runtime.h>
#include <stdint.h>

// graph_smooth: x = node_features @ Emb; A[src,dst] = w (last write wins);
// out = A^3 @ x.  N=4096, E=131072, D_EMB=128, D_OUT=64, K=3.
//
// BEST-MEASURED CONFIG (R5 = 44.7us). Launch-bound pipeline; 5 graph nodes
// is the sync floor (zero -> scatter -> hop1 -> hop2 -> hop3). Measured and
// excluded: cg::grid.sync 120us/barrier (R3), hand tree-barrier 35us/barrier
// (R6), no-LDS hops +6us (R7), split-bins/scatter-first +1.8us (R8),
// 2-rows-per-wave +8.5us (R9), atomicMax-slot dedup-in-scatter +2us (R10).
//   N0 memset(cnt,16KB) | N1 fused embed+scatter | N2 dedup+hop1 |
//   N3 hop2 | N4 hop3.
// Bins are int4 {dst, w_bits, eid, pad}; dedup (numpy last-write-wins = max
// eid per (src,dst)) runs in the wave that owns the row during hop1 and
// writes w=0 back for losers so hops 2-3 see deduped bins.

#define N_NODES 4096
#define D_EMB   128
#define D_OUT   64

#define CAP       128   // slots per row incl. duplicates; Poisson(32) tail ~1e-40
#define CAP_SHIFT 7

// ---- N1: blocks 0..1023 embed (4 waves x 1 row), blocks 1024..1535 scatter.
__global__ void embed_scatter_kernel(const float* __restrict__ nf,
                                     const float* __restrict__ emb,
                                     float* __restrict__ x,
                                     const int* __restrict__ ei,
                                     const float* __restrict__ ew, int E,
                                     int* __restrict__ cnt,
                                     int4* __restrict__ slots) {
    if (blockIdx.x < 1024) {
        // ---- embed: x[row,:] = nf[row,:] @ emb ----
        __shared__ float srow[4][D_EMB];
        int wave = threadIdx.x >> 6;
        int lane = threadIdx.x & 63;
        int row  = blockIdx.x * 4 + wave;
        float2 a = ((const float2*)(nf + (size_t)row * D_EMB))[lane];
        srow[wave][2 * lane]     = a.x;
        srow[wave][2 * lane + 1] = a.y;
        __syncthreads();
        float acc = 0.0f;
#pragma unroll 8
        for (int k = 0; k < D_EMB; ++k)
            acc = fmaf(srow[wave][k], emb[k * D_OUT + lane], acc);
        x[row * D_OUT + lane] = acc;
    } else {
        // ---- scatter: bin every edge (incl. duplicates) by src ----
        int e = (blockIdx.x - 1024) * blockDim.x + threadIdx.x;
        if (e >= E) return;
        int src = ei[e];
        int dst = ei[E + e];
        int idx = atomicAdd(&cnt[src], 1);
        if (idx < CAP) {
            int4 s;
            s.x = dst;
            s.y = __float_as_int(ew[e]);
            s.z = e;
            s.w = 0;
            slots[(src << CAP_SHIFT) + idx] = s;
        }
    }
}

// ---- N2: per-row dedup (keep max eid per dst) + hop1; one wave per row ----
__global__ void dedup_spmm_kernel(const int* __restrict__ cnt,
                                  int4* __restrict__ slots,
                                  const float* __restrict__ x,
                                  float* __restrict__ y) {
    __shared__ int   sdst[4][CAP];
    __shared__ int   seid[4][CAP];
    __shared__ float sw[4][CAP];

    int wave = threadIdx.x >> 6;
    int lane = threadIdx.x & 63;
    int row  = blockIdx.x * 4 + wave;
    int c = cnt[row];
    if (c > CAP) c = CAP;
    int4* s = slots + ((long)row << CAP_SHIFT);

#pragma unroll
    for (int half = 0; half < 2; ++half) {
        int i = lane + half * 64;
        if (i < c) {
            int4 si = s[i];
            sdst[wave][i] = si.x;
            sw[wave][i]   = __int_as_float(si.y);
            seid[wave][i] = si.z;
        }
    }
    __syncthreads();

    // dedup: entry i loses if some j has same dst and larger eid
#pragma unroll
    for (int half = 0; half < 2; ++half) {
        int i = lane + half * 64;
        if (i < c) {
            int d = sdst[wave][i], id = seid[wave][i];
            bool loser = false;
            for (int j = 0; j < c; ++j)
                loser |= (sdst[wave][j] == d) & (seid[wave][j] > id);
            if (loser) {
                sw[wave][i] = 0.0f;
                ((int*)&s[i])[1] = 0;   // hops 2-3 see deduped weight
            }
        }
    }
    __syncthreads();

    // hop 1, 8-deep gather ILP
    float acc = 0.0f;
    int i = 0;
    for (; i + 8 <= c; i += 8) {
        float vw[8], vx[8];
        int vd[8];
#pragma unroll
        for (int k = 0; k < 8; ++k) vw[k] = sw[wave][i + k];
#pragma unroll
        for (int k = 0; k < 8; ++k) vd[k] = sdst[wave][i + k];
#pragma unroll
        for (int k = 0; k < 8; ++k) vx[k] = x[vd[k] * D_OUT + lane];
#pragma unroll
        for (int k = 0; k < 8; ++k) acc = fmaf(vw[k], vx[k], acc);
    }
    for (; i < c; ++i)
        acc = fmaf(sw[wave][i], x[sdst[wave][i] * D_OUT + lane], acc);
    y[row * D_OUT + lane] = acc;
}

// ---- N3/N4: plain SpMM hop with LDS-staged bins; one wave per row ----
__global__ void spmm_kernel(const int* __restrict__ cnt,
                            const int4* __restrict__ slots,
                            const float* __restrict__ x,
                            float* __restrict__ y) {
    __shared__ int   sdst[4][CAP];
    __shared__ float sw[4][CAP];

    int wave = threadIdx.x >> 6;
    int lane = threadIdx.x & 63;
    int row  = blockIdx.x * 4 + wave;
    int c = cnt[row];
    if (c > CAP) c = CAP;
    const int4* s = slots + ((long)row << CAP_SHIFT);

#pragma unroll
    for (int half = 0; half < 2; ++half) {
        int i = lane + half * 64;
        if (i < c) {
            int4 si = s[i];
            sdst[wave][i] = si.x;
            sw[wave][i]   = __int_as_float(si.y);
        }
    }
    __syncthreads();

    float acc = 0.0f;
    int i = 0;
    for (; i + 8 <= c; i += 8) {
        float vw[8], vx[8];
        int vd[8];
#pragma unroll
        for (int k = 0; k < 8; ++k) vw[k] = sw[wave][i + k];
#pragma unroll
        for (int k = 0; k < 8; ++k) vd[k] = sdst[wave][i + k];
#pragma unroll
        for (int k = 0; k < 8; ++k) vx[k] = x[vd[k] * D_OUT + lane];
#pragma unroll
        for (int k = 0; k < 8; ++k) acc = fmaf(vw[k], vx[k], acc);
    }
    for (; i < c; ++i)
        acc = fmaf(sw[wave][i], x[sdst[wave][i] * D_OUT + lane], acc);
    y[row * D_OUT + lane] = acc;
}

extern "C" void kernel_launch(void* const* d_in, const int* in_sizes, int n_in,
                              void* d_out, int out_size, void* d_ws, size_t ws_size,
                              hipStream_t stream) {
    const float* nf  = (const float*)d_in[0];   // [N, 128]
    const float* emb = (const float*)d_in[1];   // [128, 64]
    const int*   ei  = (const int*)d_in[2];     // [2, E]
    const float* ew  = (const float*)d_in[3];   // [E]
    float* out = (float*)d_out;                 // [N, 64]

    const int E = in_sizes[3];

    // ---- workspace carve-out (256B-aligned) ----
    char* ws = (char*)d_ws;
    size_t o = 0;
    auto take = [&](size_t bytes) -> void* {
        void* p = ws + o;
        o += (bytes + 255) & ~(size_t)255;
        return p;
    };
    int*  cnt   = (int*)take((size_t)N_NODES * 4);
    int4* slots = (int4*)take((size_t)N_NODES * CAP * 16);
    float* x0   = (float*)take((size_t)N_NODES * D_OUT * 4);
    float* x1   = (float*)take((size_t)N_NODES * D_OUT * 4);

    const int TB = 256;
    const int NB = N_NODES / 4;                       // 1024
    const int SB = (E + TB - 1) / TB;                 // 512

    hipMemsetAsync(cnt, 0, (size_t)N_NODES * 4, stream);            // N0
    embed_scatter_kernel<<<NB + SB, TB, 0, stream>>>(nf, emb, x0,   // N1
                                                     ei, ew, E, cnt, slots);
    dedup_spmm_kernel<<<NB, TB, 0, stream>>>(cnt, slots, x0, x1);   // N2
    spmm_kernel<<<NB, TB, 0, stream>>>(cnt, slots, x1, x0);         // N3
    spmm_kernel<<<NB, TB, 0, stream>>>(cnt, slots, x0, out);        // N4
}